// Round 7
// baseline (352.855 us; speedup 1.0000x reference)
//
#include <hip/hip_runtime.h>

// Problem: attention, q,k,v [B=4, N=2048, H=8, D=64] fp32 -> out same.
#define B 4
#define N 2048
#define H 8
#define D 64
#define HD 512              // row stride (elements) for fixed (b,h)
#define PLS 72              // prep-kernel LDS pad stride
#define NELEM ((size_t)B * N * H * D)   // 4194304
#define NROWS ((size_t)B * H * N)       // 65536
#define SPLIT 4

typedef _Float16 half8 __attribute__((ext_vector_type(8)));
typedef _Float16 half4 __attribute__((ext_vector_type(4)));
typedef float float4_ __attribute__((ext_vector_type(4)));

// ---------------- fused prepass: K f32->f16 same layout; V -> Vt [b,h,d,n] f16 ----------------
__global__ void prep_kernel(const float* __restrict__ K, const float* __restrict__ V,
                            _Float16* __restrict__ Kf, _Float16* __restrict__ Vtr) {
    __shared__ _Float16 tile[64][PLS];
    const int t = threadIdx.x;
    if (blockIdx.x < 2048) {
        const size_t i = (size_t)blockIdx.x * 256 + t;
        const float4_* p = (const float4_*)(K + i * 8);
        float4_ a = p[0], b = p[1];
        half8 hh;
        #pragma unroll
        for (int j = 0; j < 4; ++j) { hh[j] = (_Float16)a[j]; hh[4 + j] = (_Float16)b[j]; }
        *(half8*)(Kf + i * 8) = hh;
    } else {
        const int bid = blockIdx.x - 2048;
        const int nt = bid & 31, h = (bid >> 5) & 7, b = bid >> 8;
        {
            const int i = t >> 2, c0 = (t & 3) * 16;
            const float* vp = V + (size_t)b * N * HD + (size_t)(nt * 64 + i) * HD + h * D + c0;
            #pragma unroll
            for (int j = 0; j < 4; ++j) {
                float4_ a = *(const float4_*)(vp + j * 4);
                #pragma unroll
                for (int c = 0; c < 4; ++c) tile[i][c0 + j * 4 + c] = (_Float16)a[c];
            }
        }
        __syncthreads();
        {
            const int d = t >> 2, n0 = (t & 3) * 16;
            half8 lo, hi;
            #pragma unroll
            for (int j = 0; j < 8; ++j) { lo[j] = tile[n0 + j][d]; hi[j] = tile[n0 + 8 + j][d]; }
            _Float16* op = Vtr + ((size_t)(b * H + h) * D + d) * N + nt * 64 + n0;
            *(half8*)op = lo;
            *(half8*)(op + 8) = hi;
        }
    }
}

// ---------------- async staging (chunk-swizzled, wave-split) ----------------
__device__ __forceinline__ void stage_k(const _Float16* __restrict__ Kbh, int keybase,
                                        _Float16* kb, int wave, int lane) {
    const int rsub = lane >> 3, slot = lane & 7;
    #pragma unroll
    for (int i = 0; i < 2; ++i) {
        const int row = wave * 16 + i * 8 + rsub;
        const int c = slot ^ (row & 7);
        __builtin_amdgcn_global_load_lds(
            (const __attribute__((address_space(1))) void*)(Kbh + (size_t)(keybase + row) * HD + c * 8),
            (__attribute__((address_space(3))) void*)(kb + (wave * 16 + i * 8) * 64), 16, 0, 0);
    }
}
__device__ __forceinline__ void stage_v(const _Float16* __restrict__ Vbh, int keybase,
                                        _Float16* vb, int wave, int lane) {
    const int rsub = lane >> 3, slot = lane & 7;
    #pragma unroll
    for (int i = 0; i < 2; ++i) {
        const int row = wave * 16 + i * 8 + rsub;      // d row
        const int c = slot ^ (row & 7);
        __builtin_amdgcn_global_load_lds(
            (const __attribute__((address_space(1))) void*)(Vbh + (size_t)row * N + keybase + c * 8),
            (__attribute__((address_space(3))) void*)(vb + (wave * 16 + i * 8) * 64), 16, 0, 0);
    }
}

// ---------------- main: u=4, split-K=4, single-buffered tiles, sub-phased P ----------------
__global__ __launch_bounds__(256, 4)
void fattn7_kernel(const float* __restrict__ Q, const _Float16* __restrict__ Kf,
                   const _Float16* __restrict__ Vt, _Float16* __restrict__ Op,
                   float* __restrict__ Lp)
{
    __shared__ __align__(16) _Float16 Kb[64 * 64];      // 8 KB  [key][d chunk-swizzled]
    __shared__ __align__(16) _Float16 Vb[64 * 64];      // 8 KB  [d][key chunk-swizzled]
    __shared__ __align__(16) _Float16 Pw[4][64 * 32];   // 16 KB [q][32-key subphase, granule-swizzled]

    const int tid  = threadIdx.x;
    const int wave = tid >> 6;
    const int lane = tid & 63;
    const int m    = lane & 15;
    const int quad = lane >> 4;

    const int s  = blockIdx.x & 3;        // key split quarter
    const int qt = blockIdx.x >> 2;       // q tile of 256 rows (0..7)
    const int h  = blockIdx.y;
    const int b  = blockIdx.z;
    const int q_base = qt * 256 + wave * 64;
    const int kofs = s * (N / SPLIT);     // 512 keys per split
    const int NIT = (N / SPLIT) / 64;     // 8

    const size_t bh_q = (size_t)b * N * HD + (size_t)h * D;
    const _Float16* Kbh = Kf + bh_q;
    const _Float16* Vbh = Vt + (size_t)(b * H + h) * D * N;
    _Float16* PwW = Pw[wave];

    const float SC = 0.125f * 1.4426950408889634f;
    half8 qf[4][2];
    #pragma unroll
    for (int u = 0; u < 4; ++u) {
        const float* qp = Q + bh_q + (size_t)(q_base + u * 16 + m) * HD + quad * 8;
        float4_ a0 = *(const float4_*)qp,        a1 = *(const float4_*)(qp + 4);
        float4_ b0 = *(const float4_*)(qp + 32), b1 = *(const float4_*)(qp + 36);
        #pragma unroll
        for (int jj = 0; jj < 4; ++jj) {
            qf[u][0][jj] = (_Float16)(a0[jj] * SC); qf[u][0][4 + jj] = (_Float16)(a1[jj] * SC);
            qf[u][1][jj] = (_Float16)(b0[jj] * SC); qf[u][1][4 + jj] = (_Float16)(b1[jj] * SC);
        }
    }

    float4_ o[4][4] = {};                 // C-layout: q = u*16+quad*4+r, d = db*16+m
    float lsum[4] = {0.f, 0.f, 0.f, 0.f};

    for (int t = 0; t < NIT; ++t) {
        __syncthreads();                  // protect tiles from previous iter's readers
        stage_k(Kbh, kofs + t * 64, Kb, wave, lane);
        stage_v(Vbh, kofs + t * 64, Vb, wave, lane);
        __syncthreads();                  // vmcnt(0) drain -> tiles resident

        #pragma unroll
        for (int sp = 0; sp < 2; ++sp) {
            // ---- S^T on 32 keys: A=K frag, B=Q frag; exp2; write P granule-swizzled ----
            #pragma unroll
            for (int bb = 0; bb < 2; ++bb) {
                const int key = (sp * 2 + bb) * 16 + m;
                half8 kf0 = *(const half8*)(Kb + key * 64 + ((quad ^ (m & 7)) * 8));
                half8 kf1 = *(const half8*)(Kb + key * 64 + (((4 + quad) ^ (m & 7)) * 8));
                #pragma unroll
                for (int u = 0; u < 4; ++u) {
                    float4_ acc = {};
                    acc = __builtin_amdgcn_mfma_f32_16x16x32_f16(kf0, qf[u][0], acc, 0, 0, 0);
                    acc = __builtin_amdgcn_mfma_f32_16x16x32_f16(kf1, qf[u][1], acc, 0, 0, 0);
                    half4 pk;
                    #pragma unroll
                    for (int r = 0; r < 4; ++r) {
                        float p = __builtin_amdgcn_exp2f(acc[r]);
                        lsum[u] += p;
                        pk[r] = (_Float16)p;
                    }
                    // granule g = bb*4+quad (8B), swizzled by q&7: 2-way max (free)
                    *(half4*)(PwW + (u * 16 + m) * 32 + (((bb * 4 + quad) ^ (m & 7)) * 4)) = pk;
                }
            }
            // same-wave DS ordering covers write->read (per-wave buffer)

            // ---- PV on those 32 keys: A=P frag, B=V frag ----
            half8 af[4];
            #pragma unroll
            for (int u = 0; u < 4; ++u) {
                half4 lo = *(const half4*)(PwW + (u * 16 + m) * 32 + (((2 * quad) ^ (m & 7)) * 4));
                half4 hi = *(const half4*)(PwW + (u * 16 + m) * 32 + (((2 * quad + 1) ^ (m & 7)) * 4));
                #pragma unroll
                for (int jj = 0; jj < 4; ++jj) { af[u][jj] = lo[jj]; af[u][4 + jj] = hi[jj]; }
            }
            #pragma unroll
            for (int db = 0; db < 4; ++db) {
                half8 bf = *(const half8*)(Vb + (db * 16 + m) * 64 + (((sp * 4 + quad) ^ (m & 7)) * 8));
                #pragma unroll
                for (int u = 0; u < 4; ++u)
                    o[u][db] = __builtin_amdgcn_mfma_f32_16x16x32_f16(af[u], bf, o[u][db], 0, 0, 0);
            }
        }
    }

    // ---- store f16 partial O and f32 partial l (combine normalizes) ----
    float lr[4];
    #pragma unroll
    for (int u = 0; u < 4; ++u) {
        float v = lsum[u];
        v += __shfl_xor(v, 16, 64);
        v += __shfl_xor(v, 32, 64);
        lr[u] = v;
    }
    float* Ld = Lp + (size_t)s * NROWS;
    if (lane < 16) {
        #pragma unroll
        for (int u = 0; u < 4; ++u)
            Ld[(size_t)(b * H + h) * N + q_base + u * 16 + lane] = lr[u];
    }
    _Float16* Od = Op + (size_t)s * NELEM;
    #pragma unroll
    for (int u = 0; u < 4; ++u)
        #pragma unroll
        for (int db = 0; db < 4; ++db)
            #pragma unroll
            for (int r = 0; r < 4; ++r) {
                const int row = q_base + u * 16 + quad * 4 + r;
                Od[bh_q + (size_t)row * HD + db * 16 + m] = (_Float16)o[u][db][r];
            }
}

// ---------------- combine: out = (sum_s Op[s]) / (sum_s Lp[s]) ----------------
__global__ void combine4_kernel(float* __restrict__ out, const _Float16* __restrict__ Op,
                                const float* __restrict__ Lp) {
    const size_t i = ((size_t)blockIdx.x * 256 + threadIdx.x) * 8;
    const int hh = (int)((i >> 6) & 7);
    const int nn = (int)((i >> 9) & 2047);
    const int bb = (int)(i >> 20);
    const size_t qi = ((size_t)(bb * 8 + hh) << 11) | (size_t)nn;
    const float r = 1.0f / (Lp[qi] + Lp[NROWS + qi] + Lp[2 * NROWS + qi] + Lp[3 * NROWS + qi]);
    float acc[8] = {};
    #pragma unroll
    for (int s = 0; s < 4; ++s) {
        half8 hv = *(const half8*)(Op + (size_t)s * NELEM + i);
        #pragma unroll
        for (int j = 0; j < 8; ++j) acc[j] += (float)hv[j];
    }
    float4_ r0, r1;
    #pragma unroll
    for (int j = 0; j < 4; ++j) { r0[j] = acc[j] * r; r1[j] = acc[4 + j] * r; }
    *(float4_*)(out + i) = r0;
    *(float4_*)(out + i + 4) = r1;
}

// ---------------- fattn5 (round-5 verified) as mid-fallback ----------------
__device__ __forceinline__ void do_st(const _Float16* Kt, const half8 qf[2][2],
                                      float lsum[2], _Float16* PwW, int m, int quad) {
    #pragma unroll
    for (int blk = 0; blk < 4; ++blk) {
        const int key = blk * 16 + m;
        half8 kf0 = *(const half8*)(Kt + key * 64 + ((quad ^ (m & 7)) * 8));
        half8 kf1 = *(const half8*)(Kt + key * 64 + (((4 + quad) ^ (m & 7)) * 8));
        #pragma unroll
        for (int u = 0; u < 2; ++u) {
            float4_ acc = {};
            acc = __builtin_amdgcn_mfma_f32_16x16x32_f16(kf0, qf[u][0], acc, 0, 0, 0);
            acc = __builtin_amdgcn_mfma_f32_16x16x32_f16(kf1, qf[u][1], acc, 0, 0, 0);
            half4 pk;
            #pragma unroll
            for (int r = 0; r < 4; ++r) {
                float p = __builtin_amdgcn_exp2f(acc[r]);
                lsum[u] += p;
                pk[r] = (_Float16)p;
            }
            *(half4*)(PwW + (u * 16 + m) * 64 + ((blk * 16 + quad * 4) ^ ((m & 7) << 3))) = pk;
        }
    }
}
__device__ __forceinline__ void load_af(half8 af[2][2], const _Float16* PwW, int m, int quad) {
    #pragma unroll
    for (int u = 0; u < 2; ++u)
        #pragma unroll
        for (int ks = 0; ks < 2; ++ks)
            af[u][ks] = *(const half8*)(PwW + (u * 16 + m) * 64
                                        + ((ks * 32 + quad * 8) ^ ((m & 7) << 3)));
}
__device__ __forceinline__ void do_pv(const _Float16* Vtile, const half8 af[2][2],
                                      float4_ o[2][4], int m, int quad) {
    #pragma unroll
    for (int ks = 0; ks < 2; ++ks)
        #pragma unroll
        for (int db = 0; db < 4; ++db) {
            half8 bf = *(const half8*)(Vtile + (db * 16 + m) * 64
                                       + ((((ks << 2) + quad) ^ (m & 7)) * 8));
            #pragma unroll
            for (int u = 0; u < 2; ++u)
                o[u][db] = __builtin_amdgcn_mfma_f32_16x16x32_f16(af[u][ks], bf, o[u][db], 0, 0, 0);
        }
}

__global__ __launch_bounds__(256, 2)
void fattn5_kernel(const float* __restrict__ Q, const _Float16* __restrict__ Kf,
                   const _Float16* __restrict__ Vt, float* __restrict__ Out)
{
    __shared__ __align__(16) _Float16 Kb2[2][64 * 64];
    __shared__ __align__(16) _Float16 Vb2[2][64 * 64];
    __shared__ __align__(16) _Float16 Pw2[4][32 * 64];

    const int tid  = threadIdx.x;
    const int wave = tid >> 6, lane = tid & 63;
    const int m = lane & 15, quad = lane >> 4;
    const int h = blockIdx.y, b = blockIdx.z;
    const int q_base = blockIdx.x * 128 + wave * 32;
    const size_t bh_q = (size_t)b * N * HD + (size_t)h * D;
    const _Float16* Kbh = Kf + bh_q;
    const _Float16* Vbh = Vt + (size_t)(b * H + h) * D * N;
    _Float16* PwW = Pw2[wave];
    const float SC = 0.125f * 1.4426950408889634f;
    half8 qf[2][2];
    #pragma unroll
    for (int u = 0; u < 2; ++u) {
        const float* qp = Q + bh_q + (size_t)(q_base + u * 16 + m) * HD + quad * 8;
        float4_ a0 = *(const float4_*)qp,        a1 = *(const float4_*)(qp + 4);
        float4_ b0 = *(const float4_*)(qp + 32), b1 = *(const float4_*)(qp + 36);
        #pragma unroll
        for (int jj = 0; jj < 4; ++jj) {
            qf[u][0][jj] = (_Float16)(a0[jj] * SC); qf[u][0][4 + jj] = (_Float16)(a1[jj] * SC);
            qf[u][1][jj] = (_Float16)(b0[jj] * SC); qf[u][1][4 + jj] = (_Float16)(b1[jj] * SC);
        }
    }
    float4_ o[2][4] = {};
    float lsum[2] = {0.f, 0.f};
    stage_k(Kbh, 0, Kb2[0], wave, lane);
    __syncthreads();
    stage_k(Kbh, 64, Kb2[1], wave, lane);
    stage_v(Vbh, 0, Vb2[0], wave, lane);
    do_st(Kb2[0], qf, lsum, PwW, m, quad);
    for (int t = 1; t < 32; ++t) {
        __syncthreads();
        if (t + 1 < 32) stage_k(Kbh, (t + 1) * 64, Kb2[(t + 1) & 1], wave, lane);
        stage_v(Vbh, t * 64, Vb2[t & 1], wave, lane);
        half8 af[2][2];
        load_af(af, PwW, m, quad);
        do_st(Kb2[t & 1], qf, lsum, PwW, m, quad);
        do_pv(Vb2[(t - 1) & 1], af, o, m, quad);
    }
    __syncthreads();
    {
        half8 af[2][2];
        load_af(af, PwW, m, quad);
        do_pv(Vb2[1], af, o, m, quad);
    }
    float inv[2];
    #pragma unroll
    for (int u = 0; u < 2; ++u) {
        float v = lsum[u];
        v += __shfl_xor(v, 16, 64);
        v += __shfl_xor(v, 32, 64);
        inv[u] = 1.0f / v;
    }
    #pragma unroll
    for (int u = 0; u < 2; ++u)
        #pragma unroll
        for (int r = 0; r < 4; ++r) {
            const int src = (lane & 48) | (quad * 4 + r);
            const float linv = __shfl(inv[u], src, 64);
            const int row = q_base + u * 16 + quad * 4 + r;
            #pragma unroll
            for (int db = 0; db < 4; ++db)
                Out[bh_q + (size_t)row * HD + db * 16 + m] = o[u][db][r] * linv;
        }
}

// ---------------- last-resort fallback (no workspace): round-1 kernel ----------------
__global__ __launch_bounds__(256, 2)
void fattn_fb_kernel(const float* __restrict__ Q, const float* __restrict__ K,
                     const float* __restrict__ V, float* __restrict__ Out)
{
    __shared__ __align__(16) _Float16 Ks[64][PLS];
    __shared__ __align__(16) _Float16 Vts[D][PLS];
    __shared__ __align__(16) _Float16 Pwf[4][16][PLS];
    const int tid = threadIdx.x, wave = tid >> 6, lane = tid & 63;
    const int m = lane & 15, quad = lane >> 4;
    const int q_base = blockIdx.x * 64;
    const size_t bh_off = ((size_t)blockIdx.z * N * H + (size_t)blockIdx.y) * D;
    const float SCALE = 0.125f;
    const int qrow = q_base + wave * 16 + m;
    const float* qp = Q + bh_off + (size_t)qrow * HD + quad * 8;
    half8 qf0, qf1;
    #pragma unroll
    for (int j = 0; j < 8; ++j) qf0[j] = (_Float16)(qp[j] * SCALE);
    #pragma unroll
    for (int j = 0; j < 8; ++j) qf1[j] = (_Float16)(qp[32 + j] * SCALE);
    float4_ o[4] = {};
    float mi[4], li[4];
    #pragma unroll
    for (int r = 0; r < 4; ++r) { mi[r] = -1e30f; li[r] = 0.0f; }
    for (int kt = 0; kt < N; kt += 64) {
        __syncthreads();
        {
            const int key = tid >> 2, c0 = (tid & 3) * 16;
            const float* kp = K + bh_off + (size_t)(kt + key) * HD + c0;
            half8 lo, hi;
            #pragma unroll
            for (int j = 0; j < 8; ++j) lo[j] = (_Float16)kp[j];
            #pragma unroll
            for (int j = 0; j < 8; ++j) hi[j] = (_Float16)kp[8 + j];
            *(half8*)&Ks[key][c0] = lo;
            *(half8*)&Ks[key][c0 + 8] = hi;
        }
        {
            const int c0 = (tid & 15) * 4, k0 = (tid >> 4) * 4;
            const float* vp = V + bh_off + (size_t)(kt + k0) * HD + c0;
            #pragma unroll
            for (int c = 0; c < 4; ++c)
                #pragma unroll
                for (int i = 0; i < 4; ++i)
                    Vts[c0 + c][k0 + i] = (_Float16)vp[i * HD + c];
        }
        __syncthreads();
        float4_ s[4];
        #pragma unroll
        for (int blk = 0; blk < 4; ++blk) {
            const int key = blk * 16 + m;
            half8 kf0 = *(const half8*)&Ks[key][quad * 8];
            half8 kf1 = *(const half8*)&Ks[key][32 + quad * 8];
            float4_ acc = {};
            acc = __builtin_amdgcn_mfma_f32_16x16x32_f16(qf0, kf0, acc, 0, 0, 0);
            acc = __builtin_amdgcn_mfma_f32_16x16x32_f16(qf1, kf1, acc, 0, 0, 0);
            s[blk] = acc;
        }
        float alpha[4];
        #pragma unroll
        for (int r = 0; r < 4; ++r) {
            float v0 = fmaxf(fmaxf(s[0][r], s[1][r]), fmaxf(s[2][r], s[3][r]));
            #pragma unroll
            for (int mask = 1; mask < 16; mask <<= 1) v0 = fmaxf(v0, __shfl_xor(v0, mask, 64));
            float mn = fmaxf(mi[r], v0);
            alpha[r] = __expf(mi[r] - mn);
            mi[r] = mn;
        }
        #pragma unroll
        for (int blk = 0; blk < 4; ++blk)
            #pragma unroll
            for (int r = 0; r < 4; ++r) s[blk][r] = __expf(s[blk][r] - mi[r]);
        #pragma unroll
        for (int r = 0; r < 4; ++r) {
            float tt = s[0][r] + s[1][r] + s[2][r] + s[3][r];
            #pragma unroll
            for (int mask = 1; mask < 16; mask <<= 1) tt += __shfl_xor(tt, mask, 64);
            li[r] = li[r] * alpha[r] + tt;
        }
        #pragma unroll
        for (int d = 0; d < 4; ++d)
            #pragma unroll
            for (int r = 0; r < 4; ++r) o[d][r] *= alpha[r];
        #pragma unroll
        for (int blk = 0; blk < 4; ++blk)
            #pragma unroll
            for (int r = 0; r < 4; ++r)
                Pwf[wave][quad * 4 + r][blk * 16 + m] = (_Float16)s[blk][r];
        #pragma unroll
        for (int ks = 0; ks < 2; ++ks) {
            half8 af = *(const half8*)&Pwf[wave][m][ks * 32 + quad * 8];
            #pragma unroll
            for (int d = 0; d < 4; ++d) {
                half8 bf = *(const half8*)&Vts[d * 16 + m][ks * 32 + quad * 8];
                o[d] = __builtin_amdgcn_mfma_f32_16x16x32_f16(af, bf, o[d], 0, 0, 0);
            }
        }
    }
    #pragma unroll
    for (int d = 0; d < 4; ++d)
        #pragma unroll
        for (int r = 0; r < 4; ++r) {
            const int row = q_base + wave * 16 + quad * 4 + r;
            Out[bh_off + (size_t)row * HD + d * 16 + m] = o[d][r] / li[r];
        }
}

extern "C" void kernel_launch(void* const* d_in, const int* in_sizes, int n_in,
                              void* d_out, int out_size, void* d_ws, size_t ws_size,
                              hipStream_t stream) {
    const float* q = (const float*)d_in[0];
    const float* k = (const float*)d_in[1];
    const float* v = (const float*)d_in[2];
    float* out = (float*)d_out;

    const size_t need5 = 2 * NELEM * sizeof(_Float16);                      // Kf + Vt
    const size_t need7 = need5 + SPLIT * NELEM * sizeof(_Float16)           // Op
                               + SPLIT * NROWS * sizeof(float);             // Lp

    if (ws_size >= need7) {
        _Float16* Kf  = (_Float16*)d_ws;
        _Float16* Vtr = Kf + NELEM;
        _Float16* Op  = Vtr + NELEM;
        float* Lp = (float*)(Op + SPLIT * NELEM);
        prep_kernel<<<dim3(3072), 256, 0, stream>>>(k, v, Kf, Vtr);
        fattn7_kernel<<<dim3((N / 256) * SPLIT, H, B), 256, 0, stream>>>(q, Kf, Vtr, Op, Lp);
        combine4_kernel<<<dim3(NELEM / 8 / 256), 256, 0, stream>>>(out, Op, Lp);
    } else if (ws_size >= need5) {
        _Float16* Kf  = (_Float16*)d_ws;
        _Float16* Vtr = Kf + NELEM;
        prep_kernel<<<dim3(3072), 256, 0, stream>>>(k, v, Kf, Vtr);
        fattn5_kernel<<<dim3(16, H, B), 256, 0, stream>>>(q, Kf, Vtr, out);
    } else {
        fattn_fb_kernel<<<dim3(N / 64, H, B), 256, 0, stream>>>(q, k, v, out);
    }
}

// Round 8
// 140.964 us; speedup vs baseline: 2.5032x; 2.5032x over previous
//
#include <hip/hip_runtime.h>

// Problem: attention, q,k,v [B=4, N=2048, H=8, D=64] fp32 -> out same.
#define B 4
#define N 2048
#define H 8
#define D 64
#define HD 512              // row stride (elements) for fixed (b,h)
#define PLS 72              // prep-kernel LDS pad stride
#define NELEM ((size_t)B * N * H * D)   // 4194304
#define NROWS ((size_t)B * H * N)       // 65536

typedef _Float16 half8 __attribute__((ext_vector_type(8)));
typedef _Float16 half4 __attribute__((ext_vector_type(4)));
typedef float float4_ __attribute__((ext_vector_type(4)));

// ---------------- fused prepass: K f32->f16 same layout; V -> Vt [b,h,d,n] f16 ----------------
__global__ void prep_kernel(const float* __restrict__ K, const float* __restrict__ V,
                            _Float16* __restrict__ Kf, _Float16* __restrict__ Vtr) {
    __shared__ _Float16 tile[64][PLS];
    const int t = threadIdx.x;
    if (blockIdx.x < 2048) {
        const size_t i = (size_t)blockIdx.x * 256 + t;
        const float4_* p = (const float4_*)(K + i * 8);
        float4_ a = p[0], b = p[1];
        half8 hh;
        #pragma unroll
        for (int j = 0; j < 4; ++j) { hh[j] = (_Float16)a[j]; hh[4 + j] = (_Float16)b[j]; }
        *(half8*)(Kf + i * 8) = hh;
    } else {
        const int bid = blockIdx.x - 2048;
        const int nt = bid & 31, h = (bid >> 5) & 7, b = bid >> 8;
        {
            const int i = t >> 2, c0 = (t & 3) * 16;
            const float* vp = V + (size_t)b * N * HD + (size_t)(nt * 64 + i) * HD + h * D + c0;
            #pragma unroll
            for (int j = 0; j < 4; ++j) {
                float4_ a = *(const float4_*)(vp + j * 4);
                #pragma unroll
                for (int c = 0; c < 4; ++c) tile[i][c0 + j * 4 + c] = (_Float16)a[c];
            }
        }
        __syncthreads();
        {
            const int d = t >> 2, n0 = (t & 3) * 16;
            half8 lo, hi;
            #pragma unroll
            for (int j = 0; j < 8; ++j) { lo[j] = tile[n0 + j][d]; hi[j] = tile[n0 + 8 + j][d]; }
            _Float16* op = Vtr + ((size_t)(b * H + h) * D + d) * N + nt * 64 + n0;
            *(half8*)op = lo;
            *(half8*)(op + 8) = hi;
        }
    }
}

// ---------------- async staging ----------------
// V (and fattn5's K): chunk stored at slot = chunk ^ (row&7)
__device__ __forceinline__ void stage_k(const _Float16* __restrict__ Kbh, int keybase,
                                        _Float16* kb, int wave, int lane) {
    const int rsub = lane >> 3, slot = lane & 7;
    #pragma unroll
    for (int i = 0; i < 2; ++i) {
        const int row = wave * 16 + i * 8 + rsub;
        const int c = slot ^ (row & 7);
        __builtin_amdgcn_global_load_lds(
            (const __attribute__((address_space(1))) void*)(Kbh + (size_t)(keybase + row) * HD + c * 8),
            (__attribute__((address_space(3))) void*)(kb + (wave * 16 + i * 8) * 64), 16, 0, 0);
    }
}
// fattn8 K: chunk stored at slot = chunk ^ s(row), s(row)=(row&3)|(((row>>3)&1)<<2)
__device__ __forceinline__ void stage_k8(const _Float16* __restrict__ Kbh, int keybase,
                                         _Float16* kb, int wave, int lane) {
    const int rsub = lane >> 3, slot = lane & 7;
    #pragma unroll
    for (int i = 0; i < 2; ++i) {
        const int row = wave * 16 + i * 8 + rsub;
        const int sr = (row & 3) | (((row >> 3) & 1) << 2);
        const int c = slot ^ sr;
        __builtin_amdgcn_global_load_lds(
            (const __attribute__((address_space(1))) void*)(Kbh + (size_t)(keybase + row) * HD + c * 8),
            (__attribute__((address_space(3))) void*)(kb + (wave * 16 + i * 8) * 64), 16, 0, 0);
    }
}
__device__ __forceinline__ void stage_v(const _Float16* __restrict__ Vbh, int keybase,
                                        _Float16* vb, int wave, int lane) {
    const int rsub = lane >> 3, slot = lane & 7;
    #pragma unroll
    for (int i = 0; i < 2; ++i) {
        const int row = wave * 16 + i * 8 + rsub;      // d row
        const int c = slot ^ (row & 7);
        __builtin_amdgcn_global_load_lds(
            (const __attribute__((address_space(1))) void*)(Vbh + (size_t)row * N + keybase + c * 8),
            (__attribute__((address_space(3))) void*)(vb + (wave * 16 + i * 8) * 64), 16, 0, 0);
    }
}

// ---------------- main: u=4, split-K=2, P-in-registers (permuted-key S blocks) ----------------
// S-block b of pair p computes physical keys p*32 + g*8 + b*4 + r (g=m>>2 at build,
// g=quad in C-layout). Two blocks' exp2 outputs pack into half8 pf[u] which IS a
// valid 16x16x32 B-operand (k = quad*8 + j), aligned with V^T A-fragments.
__global__ __launch_bounds__(256, 2)
void fattn8_kernel(const float* __restrict__ Q, const _Float16* __restrict__ Kf,
                   const _Float16* __restrict__ Vt, float* __restrict__ O0,
                   float* __restrict__ O1, float* __restrict__ L0, float* __restrict__ L1)
{
    __shared__ __align__(16) _Float16 Kb[2][64 * 64];   // 16 KB
    __shared__ __align__(16) _Float16 Vb[2][64 * 64];   // 16 KB

    const int tid  = threadIdx.x;
    const int wave = tid >> 6;
    const int lane = tid & 63;
    const int m    = lane & 15;
    const int quad = lane >> 4;

    const int s  = blockIdx.x & 1;        // key split half
    const int qt = blockIdx.x >> 1;       // q tile of 256 rows (0..7)
    const int h  = blockIdx.y;
    const int b  = blockIdx.z;
    const int q_base = qt * 256 + wave * 64;
    const int kofs = s * (N / 2);
    const int NIT = (N / 2) / 64;         // 16

    const size_t bh_q = (size_t)b * N * HD + (size_t)h * D;
    const _Float16* Kbh = Kf + bh_q;
    const _Float16* Vbh = Vt + (size_t)(b * H + h) * D * N;

    const float SC = 0.125f * 1.4426950408889634f;
    half8 qf[4][2];
    #pragma unroll
    for (int u = 0; u < 4; ++u) {
        const float* qp = Q + bh_q + (size_t)(q_base + u * 16 + m) * HD + quad * 8;
        float4_ a0 = *(const float4_*)qp,        a1 = *(const float4_*)(qp + 4);
        float4_ b0 = *(const float4_*)(qp + 32), b1 = *(const float4_*)(qp + 36);
        #pragma unroll
        for (int jj = 0; jj < 4; ++jj) {
            qf[u][0][jj] = (_Float16)(a0[jj] * SC); qf[u][0][4 + jj] = (_Float16)(a1[jj] * SC);
            qf[u][1][jj] = (_Float16)(b0[jj] * SC); qf[u][1][4 + jj] = (_Float16)(b1[jj] * SC);
        }
    }

    // O^T layout: lane holds q = m, d = db*16 + quad*4 + r  -> float4-contiguous in d
    float4_ o[4][4] = {};
    float lsum[4] = {0.f, 0.f, 0.f, 0.f};   // per-lane column sum for q = u*16 + m

    const int sf = (m & 3) | (((m >> 2) & 1) << 2);   // K-swizzle key for rows we read

    stage_k8(Kbh, kofs, Kb[0], wave, lane);
    stage_v(Vbh, kofs, Vb[0], wave, lane);

    for (int t = 0; t < NIT; ++t) {
        __syncthreads();   // own vmcnt drained first -> tile t resident; buf (t+1)&1 free
        if (t + 1 < NIT) {
            stage_k8(Kbh, kofs + (t + 1) * 64, Kb[(t + 1) & 1], wave, lane);
            stage_v(Vbh, kofs + (t + 1) * 64, Vb[(t + 1) & 1], wave, lane);
        }
        const _Float16* Kt = Kb[t & 1];
        const _Float16* Vtile = Vb[t & 1];

        #pragma unroll
        for (int p = 0; p < 2; ++p) {      // 32-key pair
            const int r0 = p * 32 + ((m >> 2) << 3) + (m & 3);   // block-0 key row for this lane
            half8 pf[4];
            #pragma unroll
            for (int bb = 0; bb < 2; ++bb) {
                const int row = r0 + bb * 4;
                half8 kf0 = *(const half8*)(Kt + row * 64 + ((quad ^ sf) * 8));
                half8 kf1 = *(const half8*)(Kt + row * 64 + (((4 + quad) ^ sf) * 8));
                #pragma unroll
                for (int u = 0; u < 4; ++u) {
                    float4_ acc = {};
                    acc = __builtin_amdgcn_mfma_f32_16x16x32_f16(kf0, qf[u][0], acc, 0, 0, 0);
                    acc = __builtin_amdgcn_mfma_f32_16x16x32_f16(kf1, qf[u][1], acc, 0, 0, 0);
                    #pragma unroll
                    for (int r = 0; r < 4; ++r) {
                        float pe = __builtin_amdgcn_exp2f(acc[r]);
                        lsum[u] += pe;
                        pf[u][bb * 4 + r] = (_Float16)pe;   // key = p*32 + quad*8 + bb*4 + r
                    }
                }
            }
            // PV: A = V^T frag (d on m, keys quad*8+j), B = pf  ->  O^T
            #pragma unroll
            for (int db = 0; db < 4; ++db) {
                half8 vf = *(const half8*)(Vtile + (db * 16 + m) * 64
                                           + (((p * 4 + quad) ^ (m & 7)) * 8));
                #pragma unroll
                for (int u = 0; u < 4; ++u)
                    o[u][db] = __builtin_amdgcn_mfma_f32_16x16x32_f16(vf, pf[u], o[u][db], 0, 0, 0);
            }
        }
    }

    // ---- store f32 raw partial O (float4, 64B row segments) + partial l ----
    float lr[4];
    #pragma unroll
    for (int u = 0; u < 4; ++u) {
        float v = lsum[u];
        v += __shfl_xor(v, 16, 64);
        v += __shfl_xor(v, 32, 64);
        lr[u] = v;
    }
    float* Ld = s ? L1 : L0;
    if (lane < 16) {
        #pragma unroll
        for (int u = 0; u < 4; ++u)
            Ld[(size_t)(b * H + h) * N + q_base + u * 16 + lane] = lr[u];
    }
    float* Od = s ? O1 : O0;
    #pragma unroll
    for (int u = 0; u < 4; ++u) {
        const int row = q_base + u * 16 + m;    // q = m in O^T layout
        #pragma unroll
        for (int db = 0; db < 4; ++db)
            *(float4_*)(Od + bh_q + (size_t)row * HD + db * 16 + quad * 4) = o[u][db];
    }
}

// ---------------- combine: out = (O0 + O1) / (l0 + l1) ----------------
__global__ void combine_kernel(float* __restrict__ out, const float* __restrict__ O1,
                               const float* __restrict__ L0, const float* __restrict__ L1) {
    const size_t i = ((size_t)blockIdx.x * 256 + threadIdx.x) * 4;
    const int hh = (int)((i >> 6) & 7);
    const int nn = (int)((i >> 9) & 2047);
    const int bb = (int)(i >> 20);
    const size_t qi = ((size_t)(bb * 8 + hh) << 11) | (size_t)nn;
    const float r = 1.0f / (L0[qi] + L1[qi]);
    float4_ a = *(const float4_*)(out + i);
    float4_ c = *(const float4_*)(O1 + i);
    float4_ res;
    #pragma unroll
    for (int j = 0; j < 4; ++j) res[j] = (a[j] + c[j]) * r;
    *(float4_*)(out + i) = res;
}

// ---------------- fattn5 (round-5 verified) as mid-fallback ----------------
__device__ __forceinline__ void do_st(const _Float16* Kt, const half8 qf[2][2],
                                      float lsum[2], _Float16* PwW, int m, int quad) {
    #pragma unroll
    for (int blk = 0; blk < 4; ++blk) {
        const int key = blk * 16 + m;
        half8 kf0 = *(const half8*)(Kt + key * 64 + ((quad ^ (m & 7)) * 8));
        half8 kf1 = *(const half8*)(Kt + key * 64 + (((4 + quad) ^ (m & 7)) * 8));
        #pragma unroll
        for (int u = 0; u < 2; ++u) {
            float4_ acc = {};
            acc = __builtin_amdgcn_mfma_f32_16x16x32_f16(kf0, qf[u][0], acc, 0, 0, 0);
            acc = __builtin_amdgcn_mfma_f32_16x16x32_f16(kf1, qf[u][1], acc, 0, 0, 0);
            half4 pk;
            #pragma unroll
            for (int r = 0; r < 4; ++r) {
                float p = __builtin_amdgcn_exp2f(acc[r]);
                lsum[u] += p;
                pk[r] = (_Float16)p;
            }
            *(half4*)(PwW + (u * 16 + m) * 64 + ((blk * 16 + quad * 4) ^ ((m & 7) << 3))) = pk;
        }
    }
}
__device__ __forceinline__ void load_af(half8 af[2][2], const _Float16* PwW, int m, int quad) {
    #pragma unroll
    for (int u = 0; u < 2; ++u)
        #pragma unroll
        for (int ks = 0; ks < 2; ++ks)
            af[u][ks] = *(const half8*)(PwW + (u * 16 + m) * 64
                                        + ((ks * 32 + quad * 8) ^ ((m & 7) << 3)));
}
__device__ __forceinline__ void do_pv(const _Float16* Vtile, const half8 af[2][2],
                                      float4_ o[2][4], int m, int quad) {
    #pragma unroll
    for (int ks = 0; ks < 2; ++ks)
        #pragma unroll
        for (int db = 0; db < 4; ++db) {
            half8 bf = *(const half8*)(Vtile + (db * 16 + m) * 64
                                       + ((((ks << 2) + quad) ^ (m & 7)) * 8));
            #pragma unroll
            for (int u = 0; u < 2; ++u)
                o[u][db] = __builtin_amdgcn_mfma_f32_16x16x32_f16(af[u][ks], bf, o[u][db], 0, 0, 0);
        }
}

__global__ __launch_bounds__(256, 2)
void fattn5_kernel(const float* __restrict__ Q, const _Float16* __restrict__ Kf,
                   const _Float16* __restrict__ Vt, float* __restrict__ Out)
{
    __shared__ __align__(16) _Float16 Kb2[2][64 * 64];
    __shared__ __align__(16) _Float16 Vb2[2][64 * 64];
    __shared__ __align__(16) _Float16 Pw2[4][32 * 64];

    const int tid  = threadIdx.x;
    const int wave = tid >> 6, lane = tid & 63;
    const int m = lane & 15, quad = lane >> 4;
    const int h = blockIdx.y, b = blockIdx.z;
    const int q_base = blockIdx.x * 128 + wave * 32;
    const size_t bh_q = (size_t)b * N * HD + (size_t)h * D;
    const _Float16* Kbh = Kf + bh_q;
    const _Float16* Vbh = Vt + (size_t)(b * H + h) * D * N;
    _Float16* PwW = Pw2[wave];
    const float SC = 0.125f * 1.4426950408889634f;
    half8 qf[2][2];
    #pragma unroll
    for (int u = 0; u < 2; ++u) {
        const float* qp = Q + bh_q + (size_t)(q_base + u * 16 + m) * HD + quad * 8;
        float4_ a0 = *(const float4_*)qp,        a1 = *(const float4_*)(qp + 4);
        float4_ b0 = *(const float4_*)(qp + 32), b1 = *(const float4_*)(qp + 36);
        #pragma unroll
        for (int jj = 0; jj < 4; ++jj) {
            qf[u][0][jj] = (_Float16)(a0[jj] * SC); qf[u][0][4 + jj] = (_Float16)(a1[jj] * SC);
            qf[u][1][jj] = (_Float16)(b0[jj] * SC); qf[u][1][4 + jj] = (_Float16)(b1[jj] * SC);
        }
    }
    float4_ o[2][4] = {};
    float lsum[2] = {0.f, 0.f};
    stage_k(Kbh, 0, Kb2[0], wave, lane);
    __syncthreads();
    stage_k(Kbh, 64, Kb2[1], wave, lane);
    stage_v(Vbh, 0, Vb2[0], wave, lane);
    do_st(Kb2[0], qf, lsum, PwW, m, quad);
    for (int t = 1; t < 32; ++t) {
        __syncthreads();
        if (t + 1 < 32) stage_k(Kbh, (t + 1) * 64, Kb2[(t + 1) & 1], wave, lane);
        stage_v(Vbh, t * 64, Vb2[t & 1], wave, lane);
        half8 af[2][2];
        load_af(af, PwW, m, quad);
        do_st(Kb2[t & 1], qf, lsum, PwW, m, quad);
        do_pv(Vb2[(t - 1) & 1], af, o, m, quad);
    }
    __syncthreads();
    {
        half8 af[2][2];
        load_af(af, PwW, m, quad);
        do_pv(Vb2[1], af, o, m, quad);
    }
    float inv[2];
    #pragma unroll
    for (int u = 0; u < 2; ++u) {
        float v = lsum[u];
        v += __shfl_xor(v, 16, 64);
        v += __shfl_xor(v, 32, 64);
        inv[u] = 1.0f / v;
    }
    #pragma unroll
    for (int u = 0; u < 2; ++u)
        #pragma unroll
        for (int r = 0; r < 4; ++r) {
            const int src = (lane & 48) | (quad * 4 + r);
            const float linv = __shfl(inv[u], src, 64);
            const int row = q_base + u * 16 + quad * 4 + r;
            #pragma unroll
            for (int db = 0; db < 4; ++db)
                Out[bh_q + (size_t)row * HD + db * 16 + m] = o[u][db][r] * linv;
        }
}

// ---------------- last-resort fallback (no workspace): round-1 kernel ----------------
__global__ __launch_bounds__(256, 2)
void fattn_fb_kernel(const float* __restrict__ Q, const float* __restrict__ K,
                     const float* __restrict__ V, float* __restrict__ Out)
{
    __shared__ __align__(16) _Float16 Ks[64][PLS];
    __shared__ __align__(16) _Float16 Vts[D][PLS];
    __shared__ __align__(16) _Float16 Pwf[4][16][PLS];
    const int tid = threadIdx.x, wave = tid >> 6, lane = tid & 63;
    const int m = lane & 15, quad = lane >> 4;
    const int q_base = blockIdx.x * 64;
    const size_t bh_off = ((size_t)blockIdx.z * N * H + (size_t)blockIdx.y) * D;
    const float SCALE = 0.125f;
    const int qrow = q_base + wave * 16 + m;
    const float* qp = Q + bh_off + (size_t)qrow * HD + quad * 8;
    half8 qf0, qf1;
    #pragma unroll
    for (int j = 0; j < 8; ++j) qf0[j] = (_Float16)(qp[j] * SCALE);
    #pragma unroll
    for (int j = 0; j < 8; ++j) qf1[j] = (_Float16)(qp[32 + j] * SCALE);
    float4_ o[4] = {};
    float mi[4], li[4];
    #pragma unroll
    for (int r = 0; r < 4; ++r) { mi[r] = -1e30f; li[r] = 0.0f; }
    for (int kt = 0; kt < N; kt += 64) {
        __syncthreads();
        {
            const int key = tid >> 2, c0 = (tid & 3) * 16;
            const float* kp = K + bh_off + (size_t)(kt + key) * HD + c0;
            half8 lo, hi;
            #pragma unroll
            for (int j = 0; j < 8; ++j) lo[j] = (_Float16)kp[j];
            #pragma unroll
            for (int j = 0; j < 8; ++j) hi[j] = (_Float16)kp[8 + j];
            *(half8*)&Ks[key][c0] = lo;
            *(half8*)&Ks[key][c0 + 8] = hi;
        }
        {
            const int c0 = (tid & 15) * 4, k0 = (tid >> 4) * 4;
            const float* vp = V + bh_off + (size_t)(kt + k0) * HD + c0;
            #pragma unroll
            for (int c = 0; c < 4; ++c)
                #pragma unroll
                for (int i = 0; i < 4; ++i)
                    Vts[c0 + c][k0 + i] = (_Float16)vp[i * HD + c];
        }
        __syncthreads();
        float4_ s[4];
        #pragma unroll
        for (int blk = 0; blk < 4; ++blk) {
            const int key = blk * 16 + m;
            half8 kf0 = *(const half8*)&Ks[key][quad * 8];
            half8 kf1 = *(const half8*)&Ks[key][32 + quad * 8];
            float4_ acc = {};
            acc = __builtin_amdgcn_mfma_f32_16x16x32_f16(qf0, kf0, acc, 0, 0, 0);
            acc = __builtin_amdgcn_mfma_f32_16x16x32_f16(qf1, kf1, acc, 0, 0, 0);
            s[blk] = acc;
        }
        float alpha[4];
        #pragma unroll
        for (int r = 0; r < 4; ++r) {
            float v0 = fmaxf(fmaxf(s[0][r], s[1][r]), fmaxf(s[2][r], s[3][r]));
            #pragma unroll
            for (int mask = 1; mask < 16; mask <<= 1) v0 = fmaxf(v0, __shfl_xor(v0, mask, 64));
            float mn = fmaxf(mi[r], v0);
            alpha[r] = __expf(mi[r] - mn);
            mi[r] = mn;
        }
        #pragma unroll
        for (int blk = 0; blk < 4; ++blk)
            #pragma unroll
            for (int r = 0; r < 4; ++r) s[blk][r] = __expf(s[blk][r] - mi[r]);
        #pragma unroll
        for (int r = 0; r < 4; ++r) {
            float tt = s[0][r] + s[1][r] + s[2][r] + s[3][r];
            #pragma unroll
            for (int mask = 1; mask < 16; mask <<= 1) tt += __shfl_xor(tt, mask, 64);
            li[r] = li[r] * alpha[r] + tt;
        }
        #pragma unroll
        for (int d = 0; d < 4; ++d)
            #pragma unroll
            for (int r = 0; r < 4; ++r) o[d][r] *= alpha[r];
        #pragma unroll
        for (int blk = 0; blk < 4; ++blk)
            #pragma unroll
            for (int r = 0; r < 4; ++r)
                Pwf[wave][quad * 4 + r][blk * 16 + m] = (_Float16)s[blk][r];
        #pragma unroll
        for (int ks = 0; ks < 2; ++ks) {
            half8 af = *(const half8*)&Pwf[wave][m][ks * 32 + quad * 8];
            #pragma unroll
            for (int d = 0; d < 4; ++d) {
                half8 bf = *(const half8*)&Vts[d * 16 + m][ks * 32 + quad * 8];
                o[d] = __builtin_amdgcn_mfma_f32_16x16x32_f16(af, bf, o[d], 0, 0, 0);
            }
        }
    }
    #pragma unroll
    for (int d = 0; d < 4; ++d)
        #pragma unroll
        for (int r = 0; r < 4; ++r) {
            const int row = q_base + wave * 16 + quad * 4 + r;
            Out[bh_off + (size_t)row * HD + d * 16 + m] = o[d][r] / li[r];
        }
}

extern "C" void kernel_launch(void* const* d_in, const int* in_sizes, int n_in,
                              void* d_out, int out_size, void* d_ws, size_t ws_size,
                              hipStream_t stream) {
    const float* q = (const float*)d_in[0];
    const float* k = (const float*)d_in[1];
    const float* v = (const float*)d_in[2];
    float* out = (float*)d_out;

    const size_t need5 = 2 * NELEM * sizeof(_Float16);                      // Kf + Vt
    const size_t need8 = need5 + NELEM * sizeof(float)                      // O1
                               + 2 * NROWS * sizeof(float);                 // L0, L1

    if (ws_size >= need8) {
        _Float16* Kf  = (_Float16*)d_ws;
        _Float16* Vtr = Kf + NELEM;
        float* O1 = (float*)(Vtr + NELEM);
        float* L0 = O1 + NELEM;
        float* L1 = L0 + NROWS;
        prep_kernel<<<dim3(3072), 256, 0, stream>>>(k, v, Kf, Vtr);
        fattn8_kernel<<<dim3(16, H, B), 256, 0, stream>>>(q, Kf, Vtr, out, O1, L0, L1);
        combine_kernel<<<dim3(4096), 256, 0, stream>>>(out, O1, L0, L1);
    } else if (ws_size >= need5) {
        _Float16* Kf  = (_Float16*)d_ws;
        _Float16* Vtr = Kf + NELEM;
        prep_kernel<<<dim3(3072), 256, 0, stream>>>(k, v, Kf, Vtr);
        fattn5_kernel<<<dim3(16, H, B), 256, 0, stream>>>(q, Kf, Vtr, out);
    } else {
        fattn_fb_kernel<<<dim3(N / 64, H, B), 256, 0, stream>>>(q, k, v, out);
    }
}